// Round 1
// baseline (2075.000 us; speedup 1.0000x reference)
//
#include <hip/hip_runtime.h>
#include <math.h>

// ---------------------------------------------------------------------------
// GraphAttentionEmbedding (TGN TransformerConv, H=2, C=64, D=128, EDGE_DIM=256)
// f32 correctness-first pipeline:
//   K1: q/k/v = x@W+b, skip = x@Wskip+bskip -> written straight into d_out
//   K2: e = [cos(rel_t*tw+tb) | msg] @ We        (edge GEMM, We in LDS)
//   K3: p = exp(dot(q[dst], k[src]+e)*SCALE), denom[dst] += p   (no max pass:
//       logits are tiny (std~0.5), exp cannot overflow; alpha identical)
//   K4: out[dst] += (v[src]+e) * p/denom[dst]    (hw f32 atomics)
// ---------------------------------------------------------------------------

#define SCALE_ATTN 0.125f

__device__ __forceinline__ void fma4(float4& a, float s, const float4& w) {
    a.x = fmaf(s, w.x, a.x);
    a.y = fmaf(s, w.y, a.y);
    a.z = fmaf(s, w.z, a.z);
    a.w = fmaf(s, w.w, a.w);
}

// ---------------------------------------------------------------------------
// K1: node linears. Block = 256 threads = 8 groups x 32 lanes.
// Each block covers 128 nodes (group g -> nodes base+g*16 .. +15, 4 at a time).
// Each lane owns 4 output columns (float4). One weight matrix at a time in LDS.
// ---------------------------------------------------------------------------
__global__ __launch_bounds__(256) void k_node(
    const float4* __restrict__ x4,
    const float4* __restrict__ Wq4, const float4* __restrict__ bq4,
    const float4* __restrict__ Wk4, const float4* __restrict__ bk4,
    const float4* __restrict__ Wv4, const float4* __restrict__ bv4,
    const float4* __restrict__ Ws4, const float4* __restrict__ bs4,
    float4* __restrict__ q4, float4* __restrict__ k4o,
    float4* __restrict__ v4, float4* __restrict__ skip4, int N)
{
    __shared__ float4 sW[128 * 32];   // 64 KB: one 128x128 weight matrix
    const int tid = threadIdx.x;
    const int g = tid >> 5, l = tid & 31;
    const int nodeBase = blockIdx.x * 128 + g * 16;

    const float4* Wm[4] = {Wq4, Wk4, Wv4, Ws4};
    const float4* bm[4] = {bq4, bk4, bv4, bs4};
    float4*       om[4] = {q4, k4o, v4, skip4};

    #pragma unroll 1
    for (int m = 0; m < 4; ++m) {
        __syncthreads();
        for (int i = tid; i < 128 * 32; i += 256) sW[i] = Wm[m][i];
        __syncthreads();
        const float4 bias = bm[m][l];

        #pragma unroll 1
        for (int qq = 0; qq < 16; qq += 4) {
            const int n0 = nodeBase + qq;
            int r[4];
            #pragma unroll
            for (int j = 0; j < 4; ++j) r[j] = min(n0 + j, N - 1);
            float4 acc[4];
            #pragma unroll
            for (int j = 0; j < 4; ++j) acc[j] = bias;

            #pragma unroll 4
            for (int kk = 0; kk < 32; ++kk) {
                const float4 w0 = sW[(kk * 4 + 0) * 32 + l];
                const float4 w1 = sW[(kk * 4 + 1) * 32 + l];
                const float4 w2 = sW[(kk * 4 + 2) * 32 + l];
                const float4 w3 = sW[(kk * 4 + 3) * 32 + l];
                #pragma unroll
                for (int j = 0; j < 4; ++j) {
                    const float4 xa = x4[r[j] * 32 + kk];
                    fma4(acc[j], xa.x, w0);
                    fma4(acc[j], xa.y, w1);
                    fma4(acc[j], xa.z, w2);
                    fma4(acc[j], xa.w, w3);
                }
            }
            #pragma unroll
            for (int j = 0; j < 4; ++j)
                if (n0 + j < N) om[m][(n0 + j) * 32 + l] = acc[j];
        }
    }
}

// ---------------------------------------------------------------------------
// K2: edge GEMM. e[edge] = [enc(128) | msg(128)] @ We (256x128).
// We fully staged in LDS (128 KB). 8 groups x 32 lanes, 4 edges per group per
// tile (32 edges/block-tile). enc staged per-group in LDS; msg read from
// global (broadcast, each row touched exactly once).
// ---------------------------------------------------------------------------
__global__ __launch_bounds__(256) void k_edge_gemm(
    const float4* __restrict__ msg4, const int* __restrict__ ei,
    const float* __restrict__ t, const float* __restrict__ lu,
    const float* __restrict__ tw, const float* __restrict__ tb,
    const float4* __restrict__ We4, float4* __restrict__ e4,
    int E, int numTiles)
{
    __shared__ float4 sWe[256 * 32];      // 128 KB
    __shared__ float4 sEnc[8][4][32];     // 16 KB
    const int tid = threadIdx.x;
    const int g = tid >> 5, l = tid & 31;

    for (int i = tid; i < 256 * 32; i += 256) sWe[i] = We4[i];
    __syncthreads();

    for (int tile = blockIdx.x; tile < numTiles; tile += gridDim.x) {
        const int eb = tile * 32 + g * 4;
        float* encF = (float*)&sEnc[g][0][0];

        // time encoding -> LDS scratch (4 cos per lane per edge)
        #pragma unroll
        for (int j = 0; j < 4; ++j) {
            const int e = eb + j;
            float rel = 0.f;
            if (e < E) { const int s = ei[e]; rel = t[e] - lu[s]; }
            #pragma unroll
            for (int i = 0; i < 4; ++i) {
                const int idx = i * 32 + l;
                encF[j * 128 + idx] = __cosf(fmaf(rel, tw[idx], tb[idx]));
            }
        }
        __syncthreads();

        int em[4];
        #pragma unroll
        for (int j = 0; j < 4; ++j) em[j] = min(eb + j, E - 1);

        float4 acc[4];
        #pragma unroll
        for (int j = 0; j < 4; ++j) acc[j] = make_float4(0.f, 0.f, 0.f, 0.f);

        // k = 0..127 : time-encoding half (attr from LDS scratch)
        #pragma unroll 2
        for (int kk = 0; kk < 32; ++kk) {
            const float4 w0 = sWe[(kk * 4 + 0) * 32 + l];
            const float4 w1 = sWe[(kk * 4 + 1) * 32 + l];
            const float4 w2 = sWe[(kk * 4 + 2) * 32 + l];
            const float4 w3 = sWe[(kk * 4 + 3) * 32 + l];
            #pragma unroll
            for (int j = 0; j < 4; ++j) {
                const float4 a = sEnc[g][j][kk];
                fma4(acc[j], a.x, w0);
                fma4(acc[j], a.y, w1);
                fma4(acc[j], a.z, w2);
                fma4(acc[j], a.w, w3);
            }
        }
        // k = 128..255 : msg half (attr from global, broadcast within group)
        #pragma unroll 2
        for (int kk = 0; kk < 32; ++kk) {
            const float4 w0 = sWe[(128 + kk * 4 + 0) * 32 + l];
            const float4 w1 = sWe[(128 + kk * 4 + 1) * 32 + l];
            const float4 w2 = sWe[(128 + kk * 4 + 2) * 32 + l];
            const float4 w3 = sWe[(128 + kk * 4 + 3) * 32 + l];
            #pragma unroll
            for (int j = 0; j < 4; ++j) {
                const float4 a = msg4[em[j] * 32 + kk];
                fma4(acc[j], a.x, w0);
                fma4(acc[j], a.y, w1);
                fma4(acc[j], a.z, w2);
                fma4(acc[j], a.w, w3);
            }
        }
        #pragma unroll
        for (int j = 0; j < 4; ++j)
            if (eb + j < E) e4[(eb + j) * 32 + l] = acc[j];
        __syncthreads();
    }
}

// ---------------------------------------------------------------------------
// K3: logits -> p = exp(logit), denom[dst,h] += p.  16 lanes per (edge, head).
// ---------------------------------------------------------------------------
__global__ __launch_bounds__(256) void k_logits(
    const int* __restrict__ ei,
    const float4* __restrict__ q4, const float4* __restrict__ k4,
    const float4* __restrict__ e4, float* __restrict__ p,
    float* __restrict__ denom, int E)
{
    const int unit = blockIdx.x * 16 + (threadIdx.x >> 4);
    const int lane = threadIdx.x & 15;
    if (unit >= 2 * E) return;
    const int edge = unit >> 1, h = unit & 1;
    const int src = ei[edge], dst = ei[E + edge];
    const int c = h * 16 + lane;

    const float4 qq = q4[dst * 32 + c];
    const float4 kk = k4[src * 32 + c];
    const float4 ee = e4[edge * 32 + c];
    float s = qq.x * (kk.x + ee.x) + qq.y * (kk.y + ee.y) +
              qq.z * (kk.z + ee.z) + qq.w * (kk.w + ee.w);
    s += __shfl_xor(s, 1);
    s += __shfl_xor(s, 2);
    s += __shfl_xor(s, 4);
    s += __shfl_xor(s, 8);
    if (lane == 0) {
        const float pp = __expf(s * SCALE_ATTN);
        p[edge * 2 + h] = pp;
        unsafeAtomicAdd(&denom[dst * 2 + h], pp);
    }
}

// ---------------------------------------------------------------------------
// K4: out[dst] += (v[src]+e) * alpha.  16 lanes per (edge, head), 4 atomics/lane.
// ---------------------------------------------------------------------------
__global__ __launch_bounds__(256) void k_scatter(
    const int* __restrict__ ei,
    const float4* __restrict__ v4, const float4* __restrict__ e4,
    const float* __restrict__ p, const float* __restrict__ denom,
    float* __restrict__ out, int E)
{
    const int unit = blockIdx.x * 16 + (threadIdx.x >> 4);
    const int lane = threadIdx.x & 15;
    if (unit >= 2 * E) return;
    const int edge = unit >> 1, h = unit & 1;
    const int src = ei[edge], dst = ei[E + edge];
    const float alpha = p[edge * 2 + h] / (denom[dst * 2 + h] + 1e-16f);
    const int c = h * 16 + lane;

    const float4 vv = v4[src * 32 + c];
    const float4 ee = e4[edge * 32 + c];
    float* o = out + (size_t)dst * 128 + (size_t)c * 4;
    unsafeAtomicAdd(o + 0, (vv.x + ee.x) * alpha);
    unsafeAtomicAdd(o + 1, (vv.y + ee.y) * alpha);
    unsafeAtomicAdd(o + 2, (vv.z + ee.z) * alpha);
    unsafeAtomicAdd(o + 3, (vv.w + ee.w) * alpha);
}

// ---------------------------------------------------------------------------
extern "C" void kernel_launch(void* const* d_in, const int* in_sizes, int n_in,
                              void* d_out, int out_size, void* d_ws, size_t ws_size,
                              hipStream_t stream)
{
    const float* x   = (const float*)d_in[0];
    const float* lu  = (const float*)d_in[1];
    const int*   ei  = (const int*)d_in[2];
    const float* t   = (const float*)d_in[3];
    const float* msg = (const float*)d_in[4];
    const float* tw  = (const float*)d_in[5];
    const float* tb  = (const float*)d_in[6];
    const float* Wq  = (const float*)d_in[7];
    const float* bq  = (const float*)d_in[8];
    const float* Wk  = (const float*)d_in[9];
    const float* bk  = (const float*)d_in[10];
    const float* Wv  = (const float*)d_in[11];
    const float* bv  = (const float*)d_in[12];
    const float* We  = (const float*)d_in[13];
    const float* Wsk = (const float*)d_in[14];
    const float* bsk = (const float*)d_in[15];

    const int N = in_sizes[1];   // last_update has N elements
    const int E = in_sizes[3];   // t has E elements
    float* out = (float*)d_out;

    char* ws = (char*)d_ws;
    float* q     = (float*)ws;  ws += (size_t)N * 128 * sizeof(float);
    float* k     = (float*)ws;  ws += (size_t)N * 128 * sizeof(float);
    float* v     = (float*)ws;  ws += (size_t)N * 128 * sizeof(float);
    float* e     = (float*)ws;  ws += (size_t)E * 128 * sizeof(float);
    float* p     = (float*)ws;  ws += (size_t)E * 2 * sizeof(float);
    float* denom = (float*)ws;  ws += (size_t)N * 2 * sizeof(float);

    hipMemsetAsync(denom, 0, (size_t)N * 2 * sizeof(float), stream);

    k_node<<<(N + 127) / 128, 256, 0, stream>>>(
        (const float4*)x,
        (const float4*)Wq, (const float4*)bq,
        (const float4*)Wk, (const float4*)bk,
        (const float4*)Wv, (const float4*)bv,
        (const float4*)Wsk, (const float4*)bsk,
        (float4*)q, (float4*)k, (float4*)v, (float4*)out, N);

    const int numTiles = (E + 31) / 32;
    k_edge_gemm<<<1024, 256, 0, stream>>>(
        (const float4*)msg, ei, t, lu, tw, tb,
        (const float4*)We, (float4*)e, E, numTiles);

    const int units = 2 * E;
    k_logits<<<(units + 15) / 16, 256, 0, stream>>>(
        ei, (const float4*)q, (const float4*)k, (const float4*)e, p, denom, E);

    k_scatter<<<(units + 15) / 16, 256, 0, stream>>>(
        ei, (const float4*)v, (const float4*)e, p, denom, out, E);
}

// Round 2
// 1308.287 us; speedup vs baseline: 1.5860x; 1.5860x over previous
//
#include <hip/hip_runtime.h>
#include <math.h>

// ---------------------------------------------------------------------------
// GraphAttentionEmbedding (TGN TransformerConv, H=2, C=64, D=128, EDGE_DIM=256)
//   K1  k_node:      q/k/v = x@W+b, skip -> d_out
//   K2  k_edge_gemm: e = [cos(rel_t*tw+tb) | msg] @ We     (We in LDS)
//   CSR build:       k_hist -> k_scan_partial -> k_scan_base -> k_scan_final
//                    -> k_fill   (edges grouped by dst, atomic-free aggregation)
//   K3  k_agg:       per-dst wave: logits, exp, denom, weighted sum, ONE store
// ---------------------------------------------------------------------------

#define SCALE_ATTN 0.125f
#define SCAN_CHUNK 512

__device__ __forceinline__ void fma4(float4& a, float s, const float4& w) {
    a.x = fmaf(s, w.x, a.x);
    a.y = fmaf(s, w.y, a.y);
    a.z = fmaf(s, w.z, a.z);
    a.w = fmaf(s, w.w, a.w);
}

// ---------------------------------------------------------------------------
// K1: node linears. Block = 256 threads = 8 groups x 32 lanes; 128 nodes/block.
// ---------------------------------------------------------------------------
__global__ __launch_bounds__(256) void k_node(
    const float4* __restrict__ x4,
    const float4* __restrict__ Wq4, const float4* __restrict__ bq4,
    const float4* __restrict__ Wk4, const float4* __restrict__ bk4,
    const float4* __restrict__ Wv4, const float4* __restrict__ bv4,
    const float4* __restrict__ Ws4, const float4* __restrict__ bs4,
    float4* __restrict__ q4, float4* __restrict__ k4o,
    float4* __restrict__ v4, float4* __restrict__ skip4, int N)
{
    __shared__ float4 sW[128 * 32];   // 64 KB
    const int tid = threadIdx.x;
    const int g = tid >> 5, l = tid & 31;
    const int nodeBase = blockIdx.x * 128 + g * 16;

    const float4* Wm[4] = {Wq4, Wk4, Wv4, Ws4};
    const float4* bm[4] = {bq4, bk4, bv4, bs4};
    float4*       om[4] = {q4, k4o, v4, skip4};

    #pragma unroll 1
    for (int m = 0; m < 4; ++m) {
        __syncthreads();
        for (int i = tid; i < 128 * 32; i += 256) sW[i] = Wm[m][i];
        __syncthreads();
        const float4 bias = bm[m][l];

        #pragma unroll 1
        for (int qq = 0; qq < 16; qq += 4) {
            const int n0 = nodeBase + qq;
            int r[4];
            #pragma unroll
            for (int j = 0; j < 4; ++j) r[j] = min(n0 + j, N - 1);
            float4 acc[4];
            #pragma unroll
            for (int j = 0; j < 4; ++j) acc[j] = bias;

            #pragma unroll 4
            for (int kk = 0; kk < 32; ++kk) {
                const float4 w0 = sW[(kk * 4 + 0) * 32 + l];
                const float4 w1 = sW[(kk * 4 + 1) * 32 + l];
                const float4 w2 = sW[(kk * 4 + 2) * 32 + l];
                const float4 w3 = sW[(kk * 4 + 3) * 32 + l];
                #pragma unroll
                for (int j = 0; j < 4; ++j) {
                    const float4 xa = x4[r[j] * 32 + kk];
                    fma4(acc[j], xa.x, w0);
                    fma4(acc[j], xa.y, w1);
                    fma4(acc[j], xa.z, w2);
                    fma4(acc[j], xa.w, w3);
                }
            }
            #pragma unroll
            for (int j = 0; j < 4; ++j)
                if (n0 + j < N) om[m][(n0 + j) * 32 + l] = acc[j];
        }
    }
}

// ---------------------------------------------------------------------------
// K2: edge GEMM. We fully staged in LDS (128 KB); 4 edges per 32-lane group.
// ---------------------------------------------------------------------------
__global__ __launch_bounds__(256) void k_edge_gemm(
    const float4* __restrict__ msg4, const int* __restrict__ ei,
    const float* __restrict__ t, const float* __restrict__ lu,
    const float* __restrict__ tw, const float* __restrict__ tb,
    const float4* __restrict__ We4, float4* __restrict__ e4,
    int E, int numTiles)
{
    __shared__ float4 sWe[256 * 32];      // 128 KB
    __shared__ float4 sEnc[8][4][32];     // 16 KB
    const int tid = threadIdx.x;
    const int g = tid >> 5, l = tid & 31;

    for (int i = tid; i < 256 * 32; i += 256) sWe[i] = We4[i];
    __syncthreads();

    for (int tile = blockIdx.x; tile < numTiles; tile += gridDim.x) {
        const int eb = tile * 32 + g * 4;
        float* encF = (float*)&sEnc[g][0][0];

        #pragma unroll
        for (int j = 0; j < 4; ++j) {
            const int e = eb + j;
            float rel = 0.f;
            if (e < E) { const int s = ei[e]; rel = t[e] - lu[s]; }
            #pragma unroll
            for (int i = 0; i < 4; ++i) {
                const int idx = i * 32 + l;
                encF[j * 128 + idx] = __cosf(fmaf(rel, tw[idx], tb[idx]));
            }
        }
        __syncthreads();

        int em[4];
        #pragma unroll
        for (int j = 0; j < 4; ++j) em[j] = min(eb + j, E - 1);

        float4 acc[4];
        #pragma unroll
        for (int j = 0; j < 4; ++j) acc[j] = make_float4(0.f, 0.f, 0.f, 0.f);

        #pragma unroll 2
        for (int kk = 0; kk < 32; ++kk) {
            const float4 w0 = sWe[(kk * 4 + 0) * 32 + l];
            const float4 w1 = sWe[(kk * 4 + 1) * 32 + l];
            const float4 w2 = sWe[(kk * 4 + 2) * 32 + l];
            const float4 w3 = sWe[(kk * 4 + 3) * 32 + l];
            #pragma unroll
            for (int j = 0; j < 4; ++j) {
                const float4 a = sEnc[g][j][kk];
                fma4(acc[j], a.x, w0);
                fma4(acc[j], a.y, w1);
                fma4(acc[j], a.z, w2);
                fma4(acc[j], a.w, w3);
            }
        }
        #pragma unroll 2
        for (int kk = 0; kk < 32; ++kk) {
            const float4 w0 = sWe[(128 + kk * 4 + 0) * 32 + l];
            const float4 w1 = sWe[(128 + kk * 4 + 1) * 32 + l];
            const float4 w2 = sWe[(128 + kk * 4 + 2) * 32 + l];
            const float4 w3 = sWe[(128 + kk * 4 + 3) * 32 + l];
            #pragma unroll
            for (int j = 0; j < 4; ++j) {
                const float4 a = msg4[em[j] * 32 + kk];
                fma4(acc[j], a.x, w0);
                fma4(acc[j], a.y, w1);
                fma4(acc[j], a.z, w2);
                fma4(acc[j], a.w, w3);
            }
        }
        #pragma unroll
        for (int j = 0; j < 4; ++j)
            if (eb + j < E) e4[(eb + j) * 32 + l] = acc[j];
        __syncthreads();
    }
}

// ---------------------------------------------------------------------------
// CSR build: histogram of dst, exclusive scan, fill permutation.
// ---------------------------------------------------------------------------
__global__ __launch_bounds__(256) void k_hist(
    const int* __restrict__ ei, int* __restrict__ counts, int E)
{
    int i = blockIdx.x * 256 + threadIdx.x;
    if (i < E) atomicAdd(&counts[ei[E + i]], 1);
}

__global__ __launch_bounds__(256) void k_scan_partial(
    const int* __restrict__ counts, int* __restrict__ partial, int N)
{
    const int base = blockIdx.x * SCAN_CHUNK;
    int v = 0;
    for (int i = threadIdx.x; i < SCAN_CHUNK; i += 256) {
        const int idx = base + i;
        if (idx < N) v += counts[idx];
    }
    __shared__ int red[4];
    #pragma unroll
    for (int off = 1; off < 64; off <<= 1) v += __shfl_xor(v, off);
    if ((threadIdx.x & 63) == 0) red[threadIdx.x >> 6] = v;
    __syncthreads();
    if (threadIdx.x == 0) partial[blockIdx.x] = red[0] + red[1] + red[2] + red[3];
}

__global__ __launch_bounds__(256) void k_scan_base(
    const int* __restrict__ partial, int* __restrict__ base, int nb)
{
    __shared__ int tmp[256];
    const int v = (threadIdx.x < nb) ? partial[threadIdx.x] : 0;
    tmp[threadIdx.x] = v;
    __syncthreads();
    for (int off = 1; off < 256; off <<= 1) {
        const int add = (threadIdx.x >= off) ? tmp[threadIdx.x - off] : 0;
        __syncthreads();
        tmp[threadIdx.x] += add;
        __syncthreads();
    }
    if (threadIdx.x < nb) base[threadIdx.x] = tmp[threadIdx.x] - v;
}

__global__ __launch_bounds__(256) void k_scan_final(
    const int* __restrict__ counts, const int* __restrict__ base,
    int* __restrict__ rowptr, int* __restrict__ cursor, int N)
{
    const int i0 = blockIdx.x * SCAN_CHUNK;
    __shared__ int tmp[256];
    const int ia = i0 + threadIdx.x * 2, ib = ia + 1;
    const int v0 = (ia < N) ? counts[ia] : 0;
    const int v1 = (ib < N) ? counts[ib] : 0;
    const int s = v0 + v1;
    tmp[threadIdx.x] = s;
    __syncthreads();
    for (int off = 1; off < 256; off <<= 1) {
        const int add = (threadIdx.x >= off) ? tmp[threadIdx.x - off] : 0;
        __syncthreads();
        tmp[threadIdx.x] += add;
        __syncthreads();
    }
    const int excl = tmp[threadIdx.x] - s + base[blockIdx.x];
    if (ia < N) { rowptr[ia] = excl;      cursor[ia] = excl; }
    if (ib < N) { rowptr[ib] = excl + v0; cursor[ib] = excl + v0; }
}

__global__ __launch_bounds__(256) void k_fill(
    const int* __restrict__ ei, int* __restrict__ cursor,
    int* __restrict__ perm, int E)
{
    int i = blockIdx.x * 256 + threadIdx.x;
    if (i < E) {
        const int d = ei[E + i];
        const int pos = atomicAdd(&cursor[d], 1);
        perm[pos] = i;
    }
}

// ---------------------------------------------------------------------------
// K3: fused attention aggregation. One 64-lane wave per dst node.
// Lanes 0..31 = head 0 (channels 0..63 as float2), lanes 32..63 = head 1.
// logit reduce via shfl_xor within each 32-lane half. One float2 store/lane.
// ---------------------------------------------------------------------------
__global__ __launch_bounds__(256) void k_agg(
    const int* __restrict__ ei, const int* __restrict__ perm,
    const int* __restrict__ rowptr, const int* __restrict__ counts,
    const float2* __restrict__ q2, const float2* __restrict__ k2,
    const float2* __restrict__ v2, const float2* __restrict__ e2,
    float2* __restrict__ out2, int N, int E)
{
    const int d = blockIdx.x * 4 + (threadIdx.x >> 6);
    if (d >= N) return;
    const int lane = threadIdx.x & 63;
    const int start = rowptr[d];
    const int deg = counts[d];

    const float2 qv = q2[(size_t)d * 64 + lane];
    float2 acc = make_float2(0.f, 0.f);
    float denom = 0.f;

    for (int i = 0; i < deg; ++i) {
        const int eid = perm[start + i];
        const int src = ei[eid];
        const float2 kk = k2[(size_t)src * 64 + lane];
        const float2 ee = e2[(size_t)eid * 64 + lane];
        float s = qv.x * (kk.x + ee.x) + qv.y * (kk.y + ee.y);
        s += __shfl_xor(s, 1);
        s += __shfl_xor(s, 2);
        s += __shfl_xor(s, 4);
        s += __shfl_xor(s, 8);
        s += __shfl_xor(s, 16);
        const float p = __expf(s * SCALE_ATTN);
        denom += p;
        const float2 vv = v2[(size_t)src * 64 + lane];
        acc.x = fmaf(p, vv.x + ee.x, acc.x);
        acc.y = fmaf(p, vv.y + ee.y, acc.y);
    }
    const float inv = 1.f / (denom + 1e-16f);
    const size_t o = (size_t)d * 64 + lane;
    const float2 cur = out2[o];                       // skip connection (from k_node)
    out2[o] = make_float2(fmaf(acc.x, inv, cur.x), fmaf(acc.y, inv, cur.y));
}

// ---------------------------------------------------------------------------
extern "C" void kernel_launch(void* const* d_in, const int* in_sizes, int n_in,
                              void* d_out, int out_size, void* d_ws, size_t ws_size,
                              hipStream_t stream)
{
    const float* x   = (const float*)d_in[0];
    const float* lu  = (const float*)d_in[1];
    const int*   ei  = (const int*)d_in[2];
    const float* t   = (const float*)d_in[3];
    const float* msg = (const float*)d_in[4];
    const float* tw  = (const float*)d_in[5];
    const float* tb  = (const float*)d_in[6];
    const float* Wq  = (const float*)d_in[7];
    const float* bq  = (const float*)d_in[8];
    const float* Wk  = (const float*)d_in[9];
    const float* bk  = (const float*)d_in[10];
    const float* Wv  = (const float*)d_in[11];
    const float* bv  = (const float*)d_in[12];
    const float* We  = (const float*)d_in[13];
    const float* Wsk = (const float*)d_in[14];
    const float* bsk = (const float*)d_in[15];

    const int N = in_sizes[1];   // last_update: N elements
    const int E = in_sizes[3];   // t: E elements
    float* out = (float*)d_out;

    char* ws = (char*)d_ws;
    float* q      = (float*)ws;  ws += (size_t)N * 128 * sizeof(float);
    float* k      = (float*)ws;  ws += (size_t)N * 128 * sizeof(float);
    float* v      = (float*)ws;  ws += (size_t)N * 128 * sizeof(float);
    float* e      = (float*)ws;  ws += (size_t)E * 128 * sizeof(float);
    int* counts   = (int*)ws;    ws += (size_t)N * sizeof(int);
    int* rowptr   = (int*)ws;    ws += (size_t)N * sizeof(int);
    int* cursor   = (int*)ws;    ws += (size_t)N * sizeof(int);
    int* perm     = (int*)ws;    ws += (size_t)E * sizeof(int);
    int* partial  = (int*)ws;    ws += 512 * sizeof(int);
    int* baseArr  = (int*)ws;    ws += 512 * sizeof(int);

    const int nScan = (N + SCAN_CHUNK - 1) / SCAN_CHUNK;

    hipMemsetAsync(counts, 0, (size_t)N * sizeof(int), stream);

    k_node<<<(N + 127) / 128, 256, 0, stream>>>(
        (const float4*)x,
        (const float4*)Wq, (const float4*)bq,
        (const float4*)Wk, (const float4*)bk,
        (const float4*)Wv, (const float4*)bv,
        (const float4*)Wsk, (const float4*)bsk,
        (float4*)q, (float4*)k, (float4*)v, (float4*)out, N);

    const int numTiles = (E + 31) / 32;
    k_edge_gemm<<<1024, 256, 0, stream>>>(
        (const float4*)msg, ei, t, lu, tw, tb,
        (const float4*)We, (float4*)e, E, numTiles);

    k_hist<<<(E + 255) / 256, 256, 0, stream>>>(ei, counts, E);
    k_scan_partial<<<nScan, 256, 0, stream>>>(counts, partial, N);
    k_scan_base<<<1, 256, 0, stream>>>(partial, baseArr, nScan);
    k_scan_final<<<nScan, 256, 0, stream>>>(counts, baseArr, rowptr, cursor, N);
    k_fill<<<(E + 255) / 256, 256, 0, stream>>>(ei, cursor, perm, E);

    k_agg<<<(N + 3) / 4, 256, 0, stream>>>(
        ei, perm, rowptr, counts,
        (const float2*)q, (const float2*)k, (const float2*)v, (const float2*)e,
        (float2*)out, N, E);
}

// Round 3
// 523.137 us; speedup vs baseline: 3.9665x; 2.5009x over previous
//
#include <hip/hip_runtime.h>
#include <math.h>

// ---------------------------------------------------------------------------
// GraphAttentionEmbedding (TGN TransformerConv, H=2, C=64, D=128, EDGE_DIM=256)
//   K1 k_node_mfma: q/k/v/skip via bf16 MFMA, combined W^T (bf16, swizzled) in LDS
//   K2 k_edge_mfma: e = [cos(rel_t*tw+tb) | msg] @ We via bf16 MFMA
//                   (A-frags built in registers, We^T bf16 swizzled in LDS)
//   CSR build (hist/scan/fill) then k_agg: per-dst wave, atomic-free.
//   q/k/v/e stored bf16; skip + final output f32 in d_out.
// ---------------------------------------------------------------------------

#define SCALE_ATTN 0.125f
#define SCAN_CHUNK 512

typedef __attribute__((ext_vector_type(8))) short bf16x8;
typedef __attribute__((ext_vector_type(4))) float f32x4;

union AFrag { bf16x8 v; unsigned short u[8]; };

__device__ __forceinline__ unsigned short f2bf(float f) {
    unsigned int u = __float_as_uint(f);
    u += 0x7fffu + ((u >> 16) & 1u);          // RNE
    return (unsigned short)(u >> 16);
}
__device__ __forceinline__ float bf2f(unsigned int lo16) {
    return __uint_as_float(lo16 << 16);
}

// ---------------------------------------------------------------------------
// K1: node linears via MFMA. Block=256 (4 waves), 64 nodes/block-tile.
// LDS: W^T bf16 [n=512][k=128], swizzled byte ^= (n&7)<<4.  128 KB.
// Per wave: 16 rows x 512 cols, 32 acc tiles, 4 K-steps.
// ---------------------------------------------------------------------------
__global__ __launch_bounds__(256) void k_node_mfma(
    const float4* __restrict__ x4,
    const float* __restrict__ Wq, const float* __restrict__ Wk,
    const float* __restrict__ Wv, const float* __restrict__ Ws,
    const float* __restrict__ bq, const float* __restrict__ bk,
    const float* __restrict__ bv, const float* __restrict__ bs,
    unsigned short* __restrict__ qb, unsigned short* __restrict__ kb,
    unsigned short* __restrict__ vb, float* __restrict__ outp,
    int N, int numTiles)
{
    __shared__ __align__(16) unsigned short sW[512 * 128];   // 128 KB
    const int tid = threadIdx.x;
    const int w = tid >> 6, l = tid & 63;
    const int l15 = l & 15, lg = l >> 4;

    // stage combined W^T (bf16, swizzled): rows n: 0-127 q,128-255 k,256-383 v,384-511 skip
    for (int c = tid; c < 8192; c += 256) {
        const int n = c >> 4, kc = c & 15, k0 = kc << 3;
        const float* Wsrc = (n < 256) ? (n < 128 ? Wq : Wk) : (n < 384 ? Wv : Ws);
        const int col = n & 127;
        AFrag af;
        #pragma unroll
        for (int j = 0; j < 8; ++j) af.u[j] = f2bf(Wsrc[(k0 + j) * 128 + col]);
        const int byteoff = ((n << 8) + (k0 << 1)) ^ ((n & 7) << 4);
        *(bf16x8*)((char*)sW + byteoff) = af.v;
    }
    __syncthreads();

    for (int tile = blockIdx.x; tile < numTiles; tile += gridDim.x) {
        const int arow = tile * 64 + w * 16 + l15;
        const int na = min(arow, N - 1);

        f32x4 acc[32];
        #pragma unroll
        for (int i = 0; i < 32; ++i) acc[i] = (f32x4)(0.f);

        #pragma unroll
        for (int kk = 0; kk < 4; ++kk) {
            const int kbase = (kk << 5) + (lg << 3);
            const float4 x0 = x4[(size_t)na * 32 + (kbase >> 2)];
            const float4 x1 = x4[(size_t)na * 32 + (kbase >> 2) + 1];
            AFrag a;
            a.u[0] = f2bf(x0.x); a.u[1] = f2bf(x0.y);
            a.u[2] = f2bf(x0.z); a.u[3] = f2bf(x0.w);
            a.u[4] = f2bf(x1.x); a.u[5] = f2bf(x1.y);
            a.u[6] = f2bf(x1.z); a.u[7] = f2bf(x1.w);
            const int bbase = ((l15 << 8) + (kbase << 1)) ^ ((l & 7) << 4);
            #pragma unroll
            for (int nt = 0; nt < 32; ++nt) {
                const bf16x8 b = *(const bf16x8*)((const char*)sW + (bbase + (nt << 12)));
                acc[nt] = __builtin_amdgcn_mfma_f32_16x16x32_bf16(a.v, b, acc[nt], 0, 0, 0);
            }
        }

        const int drow0 = tile * 64 + w * 16 + (lg << 2);
        #pragma unroll
        for (int nt = 0; nt < 32; ++nt) {
            const int col = (nt << 4) + l15;       // 0..511
            float bias;
            unsigned short* dst16 = nullptr;
            int dcol = 0;
            if (nt < 8)       { bias = bq[col];       dst16 = qb; dcol = col; }
            else if (nt < 16) { bias = bk[col - 128]; dst16 = kb; dcol = col - 128; }
            else if (nt < 24) { bias = bv[col - 256]; dst16 = vb; dcol = col - 256; }
            else              { bias = bs[col - 384]; }
            #pragma unroll
            for (int r = 0; r < 4; ++r) {
                const int node = drow0 + r;
                if (node < N) {
                    const float val = acc[nt][r] + bias;
                    if (nt < 24) dst16[(size_t)node * 128 + dcol] = f2bf(val);
                    else         outp[(size_t)node * 128 + (col - 384)] = val;
                }
            }
        }
    }
}

// ---------------------------------------------------------------------------
// K2: edge GEMM via MFMA. Block=256 (4 waves), 64 edges/block-tile.
// LDS: We^T bf16 [n=128][k=256], swizzled.  64 KB -> 2 blocks/CU.
// A-frags in registers: k<128 cos time-enc, k>=128 msg (f32 -> bf16).
// ---------------------------------------------------------------------------
__global__ __launch_bounds__(256) void k_edge_mfma(
    const float4* __restrict__ msg4, const int* __restrict__ ei,
    const float* __restrict__ t, const float* __restrict__ lu,
    const float4* __restrict__ tw4, const float4* __restrict__ tb4,
    const float* __restrict__ We,
    unsigned short* __restrict__ ebuf, int E, int numTiles)
{
    __shared__ __align__(16) unsigned short sWe[128 * 256];   // 64 KB
    const int tid = threadIdx.x;
    const int w = tid >> 6, l = tid & 63;
    const int l15 = l & 15, lg = l >> 4;

    for (int c = tid; c < 4096; c += 256) {
        const int n = c >> 5, kc = c & 31, k0 = kc << 3;
        AFrag af;
        #pragma unroll
        for (int j = 0; j < 8; ++j) af.u[j] = f2bf(We[(k0 + j) * 128 + n]);
        const int byteoff = ((n << 9) + (k0 << 1)) ^ ((n & 7) << 4);
        *(bf16x8*)((char*)sWe + byteoff) = af.v;
    }
    __syncthreads();

    for (int tile = blockIdx.x; tile < numTiles; tile += gridDim.x) {
        const int arow = tile * 64 + w * 16 + l15;
        const int ea = min(arow, E - 1);
        const int srcn = ei[ea];
        const float rel = t[ea] - lu[srcn];

        f32x4 acc[8];
        #pragma unroll
        for (int i = 0; i < 8; ++i) acc[i] = (f32x4)(0.f);

        // k = 0..127: time encoding half
        #pragma unroll
        for (int kk = 0; kk < 4; ++kk) {
            const int kbase = (kk << 5) + (lg << 3);
            const float4 tww = tw4[kbase >> 2];
            const float4 tw2 = tw4[(kbase >> 2) + 1];
            const float4 tbb = tb4[kbase >> 2];
            const float4 tb2 = tb4[(kbase >> 2) + 1];
            AFrag a;
            a.u[0] = f2bf(__cosf(fmaf(rel, tww.x, tbb.x)));
            a.u[1] = f2bf(__cosf(fmaf(rel, tww.y, tbb.y)));
            a.u[2] = f2bf(__cosf(fmaf(rel, tww.z, tbb.z)));
            a.u[3] = f2bf(__cosf(fmaf(rel, tww.w, tbb.w)));
            a.u[4] = f2bf(__cosf(fmaf(rel, tw2.x, tb2.x)));
            a.u[5] = f2bf(__cosf(fmaf(rel, tw2.y, tb2.y)));
            a.u[6] = f2bf(__cosf(fmaf(rel, tw2.z, tb2.z)));
            a.u[7] = f2bf(__cosf(fmaf(rel, tw2.w, tb2.w)));
            const int bbase = ((l15 << 9) + (kbase << 1)) ^ ((l & 7) << 4);
            #pragma unroll
            for (int nt = 0; nt < 8; ++nt) {
                const bf16x8 b = *(const bf16x8*)((const char*)sWe + (bbase + (nt << 13)));
                acc[nt] = __builtin_amdgcn_mfma_f32_16x16x32_bf16(a.v, b, acc[nt], 0, 0, 0);
            }
        }
        // k = 128..255: msg half
        #pragma unroll
        for (int kk = 0; kk < 4; ++kk) {
            const int km = (kk << 5) + (lg << 3);
            const float4 m0 = msg4[(size_t)ea * 32 + (km >> 2)];
            const float4 m1 = msg4[(size_t)ea * 32 + (km >> 2) + 1];
            AFrag a;
            a.u[0] = f2bf(m0.x); a.u[1] = f2bf(m0.y);
            a.u[2] = f2bf(m0.z); a.u[3] = f2bf(m0.w);
            a.u[4] = f2bf(m1.x); a.u[5] = f2bf(m1.y);
            a.u[6] = f2bf(m1.z); a.u[7] = f2bf(m1.w);
            const int bbase = ((l15 << 9) + ((128 + km) << 1)) ^ ((l & 7) << 4);
            #pragma unroll
            for (int nt = 0; nt < 8; ++nt) {
                const bf16x8 b = *(const bf16x8*)((const char*)sWe + (bbase + (nt << 13)));
                acc[nt] = __builtin_amdgcn_mfma_f32_16x16x32_bf16(a.v, b, acc[nt], 0, 0, 0);
            }
        }
        // epilogue: store e as bf16
        const int drow0 = tile * 64 + w * 16 + (lg << 2);
        #pragma unroll
        for (int nt = 0; nt < 8; ++nt) {
            const int col = (nt << 4) + l15;
            #pragma unroll
            for (int r = 0; r < 4; ++r) {
                const int erow = drow0 + r;
                if (erow < E) ebuf[(size_t)erow * 128 + col] = f2bf(acc[nt][r]);
            }
        }
    }
}

// ---------------------------------------------------------------------------
// CSR build: histogram of dst, exclusive scan, fill permutation.
// ---------------------------------------------------------------------------
__global__ __launch_bounds__(256) void k_hist(
    const int* __restrict__ ei, int* __restrict__ counts, int E)
{
    int i = blockIdx.x * 256 + threadIdx.x;
    if (i < E) atomicAdd(&counts[ei[E + i]], 1);
}

__global__ __launch_bounds__(256) void k_scan_partial(
    const int* __restrict__ counts, int* __restrict__ partial, int N)
{
    const int base = blockIdx.x * SCAN_CHUNK;
    int v = 0;
    for (int i = threadIdx.x; i < SCAN_CHUNK; i += 256) {
        const int idx = base + i;
        if (idx < N) v += counts[idx];
    }
    __shared__ int red[4];
    #pragma unroll
    for (int off = 1; off < 64; off <<= 1) v += __shfl_xor(v, off);
    if ((threadIdx.x & 63) == 0) red[threadIdx.x >> 6] = v;
    __syncthreads();
    if (threadIdx.x == 0) partial[blockIdx.x] = red[0] + red[1] + red[2] + red[3];
}

__global__ __launch_bounds__(256) void k_scan_base(
    const int* __restrict__ partial, int* __restrict__ base, int nb)
{
    __shared__ int tmp[256];
    const int v = (threadIdx.x < nb) ? partial[threadIdx.x] : 0;
    tmp[threadIdx.x] = v;
    __syncthreads();
    for (int off = 1; off < 256; off <<= 1) {
        const int add = (threadIdx.x >= off) ? tmp[threadIdx.x - off] : 0;
        __syncthreads();
        tmp[threadIdx.x] += add;
        __syncthreads();
    }
    if (threadIdx.x < nb) base[threadIdx.x] = tmp[threadIdx.x] - v;
}

__global__ __launch_bounds__(256) void k_scan_final(
    const int* __restrict__ counts, const int* __restrict__ base,
    int* __restrict__ rowptr, int* __restrict__ cursor, int N)
{
    const int i0 = blockIdx.x * SCAN_CHUNK;
    __shared__ int tmp[256];
    const int ia = i0 + threadIdx.x * 2, ib = ia + 1;
    const int v0 = (ia < N) ? counts[ia] : 0;
    const int v1 = (ib < N) ? counts[ib] : 0;
    const int s = v0 + v1;
    tmp[threadIdx.x] = s;
    __syncthreads();
    for (int off = 1; off < 256; off <<= 1) {
        const int add = (threadIdx.x >= off) ? tmp[threadIdx.x - off] : 0;
        __syncthreads();
        tmp[threadIdx.x] += add;
        __syncthreads();
    }
    const int excl = tmp[threadIdx.x] - s + base[blockIdx.x];
    if (ia < N) { rowptr[ia] = excl;      cursor[ia] = excl; }
    if (ib < N) { rowptr[ib] = excl + v0; cursor[ib] = excl + v0; }
}

__global__ __launch_bounds__(256) void k_fill(
    const int* __restrict__ ei, int* __restrict__ cursor,
    int* __restrict__ perm, int E)
{
    int i = blockIdx.x * 256 + threadIdx.x;
    if (i < E) {
        const int d = ei[E + i];
        const int pos = atomicAdd(&cursor[d], 1);
        perm[pos] = i;
    }
}

// ---------------------------------------------------------------------------
// K3: fused attention aggregation. One 64-lane wave per dst node.
// Lanes 0..31 = head 0 (channels 0..63 as bf16 pairs), lanes 32..63 = head 1.
// q/k/v/e read as packed bf16 pairs (uint). One float2 store per lane.
// ---------------------------------------------------------------------------
__global__ __launch_bounds__(256) void k_agg(
    const int* __restrict__ ei, const int* __restrict__ perm,
    const int* __restrict__ rowptr, const int* __restrict__ counts,
    const unsigned int* __restrict__ qb, const unsigned int* __restrict__ kb,
    const unsigned int* __restrict__ vb, const unsigned int* __restrict__ eb,
    float2* __restrict__ out2, int N, int E)
{
    const int d = blockIdx.x * 4 + (threadIdx.x >> 6);
    if (d >= N) return;
    const int lane = threadIdx.x & 63;
    const int start = rowptr[d];
    const int deg = counts[d];

    const unsigned int qu = qb[(size_t)d * 64 + lane];
    const float qx = bf2f(qu & 0xffffu), qy = bf2f(qu >> 16);
    float accx = 0.f, accy = 0.f;
    float denom = 0.f;

    for (int i = 0; i < deg; ++i) {
        const int eid = perm[start + i];
        const int src = ei[eid];
        const unsigned int ku = kb[(size_t)src * 64 + lane];
        const unsigned int eu = eb[(size_t)eid * 64 + lane];
        const float kex = bf2f(ku & 0xffffu) + bf2f(eu & 0xffffu);
        const float key = bf2f(ku >> 16) + bf2f(eu >> 16);
        float s = qx * kex + qy * key;
        s += __shfl_xor(s, 1);
        s += __shfl_xor(s, 2);
        s += __shfl_xor(s, 4);
        s += __shfl_xor(s, 8);
        s += __shfl_xor(s, 16);
        const float p = __expf(s * SCALE_ATTN);
        denom += p;
        const unsigned int vu = vb[(size_t)src * 64 + lane];
        accx = fmaf(p, bf2f(vu & 0xffffu) + bf2f(eu & 0xffffu), accx);
        accy = fmaf(p, bf2f(vu >> 16) + bf2f(eu >> 16), accy);
    }
    const float inv = 1.f / (denom + 1e-16f);
    const size_t o = (size_t)d * 64 + lane;
    const float2 cur = out2[o];                  // skip connection (from k_node)
    out2[o] = make_float2(fmaf(accx, inv, cur.x), fmaf(accy, inv, cur.y));
}

// ---------------------------------------------------------------------------
extern "C" void kernel_launch(void* const* d_in, const int* in_sizes, int n_in,
                              void* d_out, int out_size, void* d_ws, size_t ws_size,
                              hipStream_t stream)
{
    const float* x   = (const float*)d_in[0];
    const float* lu  = (const float*)d_in[1];
    const int*   ei  = (const int*)d_in[2];
    const float* t   = (const float*)d_in[3];
    const float* msg = (const float*)d_in[4];
    const float* tw  = (const float*)d_in[5];
    const float* tb  = (const float*)d_in[6];
    const float* Wq  = (const float*)d_in[7];
    const float* bq  = (const float*)d_in[8];
    const float* Wk  = (const float*)d_in[9];
    const float* bk  = (const float*)d_in[10];
    const float* Wv  = (const float*)d_in[11];
    const float* bv  = (const float*)d_in[12];
    const float* We  = (const float*)d_in[13];
    const float* Wsk = (const float*)d_in[14];
    const float* bsk = (const float*)d_in[15];

    const int N = in_sizes[1];   // last_update: N elements
    const int E = in_sizes[3];   // t: E elements
    float* out = (float*)d_out;

    char* ws = (char*)d_ws;
    unsigned short* qb = (unsigned short*)ws;  ws += (size_t)N * 128 * sizeof(unsigned short);
    unsigned short* kb = (unsigned short*)ws;  ws += (size_t)N * 128 * sizeof(unsigned short);
    unsigned short* vb = (unsigned short*)ws;  ws += (size_t)N * 128 * sizeof(unsigned short);
    unsigned short* eb = (unsigned short*)ws;  ws += (size_t)E * 128 * sizeof(unsigned short);
    int* counts   = (int*)ws;    ws += (size_t)N * sizeof(int);
    int* rowptr   = (int*)ws;    ws += (size_t)N * sizeof(int);
    int* cursor   = (int*)ws;    ws += (size_t)N * sizeof(int);
    int* perm     = (int*)ws;    ws += (size_t)E * sizeof(int);
    int* partial  = (int*)ws;    ws += 512 * sizeof(int);
    int* baseArr  = (int*)ws;    ws += 512 * sizeof(int);

    const int nScan = (N + SCAN_CHUNK - 1) / SCAN_CHUNK;

    hipMemsetAsync(counts, 0, (size_t)N * sizeof(int), stream);

    const int nTilesN = (N + 63) / 64;
    k_node_mfma<<<min(nTilesN, 256), 256, 0, stream>>>(
        (const float4*)x, Wq, Wk, Wv, Wsk, bq, bk, bv, bsk,
        qb, kb, vb, out, N, nTilesN);

    const int nTilesE = (E + 63) / 64;
    k_edge_mfma<<<min(nTilesE, 512), 256, 0, stream>>>(
        (const float4*)msg, ei, t, lu,
        (const float4*)tw, (const float4*)tb, We,
        eb, E, nTilesE);

    k_hist<<<(E + 255) / 256, 256, 0, stream>>>(ei, counts, E);
    k_scan_partial<<<nScan, 256, 0, stream>>>(counts, partial, N);
    k_scan_base<<<1, 256, 0, stream>>>(partial, baseArr, nScan);
    k_scan_final<<<nScan, 256, 0, stream>>>(counts, baseArr, rowptr, cursor, N);
    k_fill<<<(E + 255) / 256, 256, 0, stream>>>(ei, cursor, perm, E);

    k_agg<<<(N + 3) / 4, 256, 0, stream>>>(
        ei, perm, rowptr, counts,
        (const unsigned int*)qb, (const unsigned int*)kb,
        (const unsigned int*)vb, (const unsigned int*)eb,
        (float2*)out, N, E);
}

// Round 4
// 439.960 us; speedup vs baseline: 4.7163x; 1.1891x over previous
//
#include <hip/hip_runtime.h>
#include <math.h>

// ---------------------------------------------------------------------------
// GraphAttentionEmbedding (TGN TransformerConv, H=2, C=64, D=128, EDGE_DIM=256)
//   CSR build: hist -> scan -> fill (fill also emits src_perm, rel_perm)
//   K1 k_node_mfma x2: [q|k] then [v|skip] via bf16 MFMA, 64 KB W^T in LDS,
//                      512-thr blocks, launch_bounds(512,4) -> 16 waves/CU
//   K2 k_edge_mfma: e[slot] = [cos(rel)|msg[perm[slot]]] @ We, CSR-slot order
//                   -> k_agg reads e/src SEQUENTIALLY (randomness lives here)
//   K3 k_agg: wave per dst, 2 edges/iter (lane = e2 x head x 4ch), no atomics
// ---------------------------------------------------------------------------

#define SCALE_ATTN 0.125f
#define SCAN_CHUNK 512

typedef __attribute__((ext_vector_type(8))) short bf16x8;
typedef __attribute__((ext_vector_type(4))) float f32x4;

union AFrag { bf16x8 v; unsigned short u[8]; };

__device__ __forceinline__ unsigned short f2bf(float f) {
    unsigned int u = __float_as_uint(f);
    u += 0x7fffu + ((u >> 16) & 1u);          // RNE
    return (unsigned short)(u >> 16);
}
__device__ __forceinline__ float bf2f(unsigned int lo16) {
    return __uint_as_float(lo16 << 16);
}
__device__ __forceinline__ float4 unpack4(uint2 u) {
    return make_float4(bf2f(u.x & 0xffffu), bf2f(u.x >> 16),
                       bf2f(u.y & 0xffffu), bf2f(u.y >> 16));
}

// ---------------------------------------------------------------------------
// K1: node linears via MFMA, one 256-col pair per launch.
// LDS: W^T bf16 [n=256][k=128] swizzled (64 KB). 512 thr = 8 waves,
// tile = 128 nodes. acc[16] f32x4 = 64 VGPR. 2 blocks/CU -> 4 waves/SIMD.
// cols 0..127 -> o0 (bf16); cols 128..255 -> of1 ? f32 : o1 (bf16).
// ---------------------------------------------------------------------------
__global__ __launch_bounds__(512, 4) void k_node_mfma(
    const float4* __restrict__ x4,
    const float* __restrict__ W0, const float* __restrict__ W1,
    const float* __restrict__ b0, const float* __restrict__ b1,
    unsigned short* __restrict__ o0, unsigned short* __restrict__ o1,
    float* __restrict__ of1,
    int N, int numTiles)
{
    __shared__ __align__(16) unsigned short sW[256 * 128];   // 64 KB
    const int tid = threadIdx.x;
    const int w = tid >> 6, l = tid & 63;
    const int l15 = l & 15, lg = l >> 4;

    for (int c = tid; c < 4096; c += 512) {
        const int n = c >> 4, k0 = (c & 15) << 3;
        const float* Wsrc = (n < 128) ? W0 : W1;
        const int col = n & 127;
        AFrag af;
        #pragma unroll
        for (int j = 0; j < 8; ++j) af.u[j] = f2bf(Wsrc[(k0 + j) * 128 + col]);
        const int byteoff = ((n << 8) + (k0 << 1)) ^ ((n & 7) << 4);
        *(bf16x8*)((char*)sW + byteoff) = af.v;
    }
    __syncthreads();

    for (int tile = blockIdx.x; tile < numTiles; tile += gridDim.x) {
        const int arow = tile * 128 + w * 16 + l15;
        const int na = min(arow, N - 1);

        f32x4 acc[16];
        #pragma unroll
        for (int i = 0; i < 16; ++i) acc[i] = (f32x4)(0.f);

        #pragma unroll 2
        for (int kk = 0; kk < 4; ++kk) {
            const int kbase = (kk << 5) + (lg << 3);
            const float4 x0 = x4[(size_t)na * 32 + (kbase >> 2)];
            const float4 x1 = x4[(size_t)na * 32 + (kbase >> 2) + 1];
            AFrag a;
            a.u[0] = f2bf(x0.x); a.u[1] = f2bf(x0.y);
            a.u[2] = f2bf(x0.z); a.u[3] = f2bf(x0.w);
            a.u[4] = f2bf(x1.x); a.u[5] = f2bf(x1.y);
            a.u[6] = f2bf(x1.z); a.u[7] = f2bf(x1.w);
            const int bbase = ((l15 << 8) + (kbase << 1)) ^ ((l & 7) << 4);
            #pragma unroll
            for (int nt = 0; nt < 16; ++nt) {
                const bf16x8 b = *(const bf16x8*)((const char*)sW + (bbase + (nt << 12)));
                acc[nt] = __builtin_amdgcn_mfma_f32_16x16x32_bf16(a.v, b, acc[nt], 0, 0, 0);
            }
        }

        const int drow0 = tile * 128 + w * 16 + (lg << 2);
        #pragma unroll
        for (int nt = 0; nt < 16; ++nt) {
            const int col = (nt << 4) + l15;        // 0..255
            const int c128 = col & 127;
            const float bias = (col < 128) ? b0[c128] : b1[c128];
            #pragma unroll
            for (int r = 0; r < 4; ++r) {
                const int node = drow0 + r;
                if (node < N) {
                    const float val = acc[nt][r] + bias;
                    if (col < 128)   o0[(size_t)node * 128 + c128] = f2bf(val);
                    else if (of1)    of1[(size_t)node * 128 + c128] = val;
                    else             o1[(size_t)node * 128 + c128] = f2bf(val);
                }
            }
        }
    }
}

// ---------------------------------------------------------------------------
// K2: edge GEMM via MFMA, CSR-slot order. LDS: We^T bf16 [n=128][k=256]
// swizzled (64 KB). 512 thr = 8 waves, tile = 128 slots. acc[8]/wave.
// A-frags in registers: k<128 cos(rel*tw+tb), k>=128 msg[perm[slot]].
// Writes e sequentially by slot (bf16).
// ---------------------------------------------------------------------------
__global__ __launch_bounds__(512, 4) void k_edge_mfma(
    const float4* __restrict__ msg4,
    const int* __restrict__ perm, const float* __restrict__ relp,
    const float4* __restrict__ tw4, const float4* __restrict__ tb4,
    const float* __restrict__ We,
    unsigned short* __restrict__ ebuf, int E, int numTiles)
{
    __shared__ __align__(16) unsigned short sWe[128 * 256];   // 64 KB
    const int tid = threadIdx.x;
    const int w = tid >> 6, l = tid & 63;
    const int l15 = l & 15, lg = l >> 4;

    for (int c = tid; c < 4096; c += 512) {
        const int n = c >> 5, k0 = (c & 31) << 3;
        AFrag af;
        #pragma unroll
        for (int j = 0; j < 8; ++j) af.u[j] = f2bf(We[(k0 + j) * 128 + n]);
        const int byteoff = ((n << 9) + (k0 << 1)) ^ ((n & 7) << 4);
        *(bf16x8*)((char*)sWe + byteoff) = af.v;
    }
    __syncthreads();

    for (int tile = blockIdx.x; tile < numTiles; tile += gridDim.x) {
        const int slot = tile * 128 + w * 16 + l15;
        const int sa = min(slot, E - 1);
        const int eid = perm[sa];
        const float rel = relp[sa];

        f32x4 acc[8];
        #pragma unroll
        for (int i = 0; i < 8; ++i) acc[i] = (f32x4)(0.f);

        // k = 0..127: time-encoding half
        #pragma unroll 2
        for (int kk = 0; kk < 4; ++kk) {
            const int kbase = (kk << 5) + (lg << 3);
            const float4 tww = tw4[kbase >> 2];
            const float4 tw2 = tw4[(kbase >> 2) + 1];
            const float4 tbb = tb4[kbase >> 2];
            const float4 tb2 = tb4[(kbase >> 2) + 1];
            AFrag a;
            a.u[0] = f2bf(__cosf(fmaf(rel, tww.x, tbb.x)));
            a.u[1] = f2bf(__cosf(fmaf(rel, tww.y, tbb.y)));
            a.u[2] = f2bf(__cosf(fmaf(rel, tww.z, tbb.z)));
            a.u[3] = f2bf(__cosf(fmaf(rel, tww.w, tbb.w)));
            a.u[4] = f2bf(__cosf(fmaf(rel, tw2.x, tb2.x)));
            a.u[5] = f2bf(__cosf(fmaf(rel, tw2.y, tb2.y)));
            a.u[6] = f2bf(__cosf(fmaf(rel, tw2.z, tb2.z)));
            a.u[7] = f2bf(__cosf(fmaf(rel, tw2.w, tb2.w)));
            const int bbase = ((l15 << 9) + (kbase << 1)) ^ ((l & 7) << 4);
            #pragma unroll
            for (int nt = 0; nt < 8; ++nt) {
                const bf16x8 b = *(const bf16x8*)((const char*)sWe + (bbase + (nt << 13)));
                acc[nt] = __builtin_amdgcn_mfma_f32_16x16x32_bf16(a.v, b, acc[nt], 0, 0, 0);
            }
        }
        // k = 128..255: msg half (random row via perm; full 512 B rows used)
        #pragma unroll 2
        for (int kk = 0; kk < 4; ++kk) {
            const int km = (kk << 5) + (lg << 3);
            const float4 m0 = msg4[(size_t)eid * 32 + (km >> 2)];
            const float4 m1 = msg4[(size_t)eid * 32 + (km >> 2) + 1];
            AFrag a;
            a.u[0] = f2bf(m0.x); a.u[1] = f2bf(m0.y);
            a.u[2] = f2bf(m0.z); a.u[3] = f2bf(m0.w);
            a.u[4] = f2bf(m1.x); a.u[5] = f2bf(m1.y);
            a.u[6] = f2bf(m1.z); a.u[7] = f2bf(m1.w);
            const int bbase = ((l15 << 9) + ((128 + km) << 1)) ^ ((l & 7) << 4);
            #pragma unroll
            for (int nt = 0; nt < 8; ++nt) {
                const bf16x8 b = *(const bf16x8*)((const char*)sWe + (bbase + (nt << 13)));
                acc[nt] = __builtin_amdgcn_mfma_f32_16x16x32_bf16(a.v, b, acc[nt], 0, 0, 0);
            }
        }
        // epilogue: store e (bf16) at CSR slot rows
        const int drow0 = tile * 128 + w * 16 + (lg << 2);
        #pragma unroll
        for (int nt = 0; nt < 8; ++nt) {
            const int col = (nt << 4) + l15;
            #pragma unroll
            for (int r = 0; r < 4; ++r) {
                const int erow = drow0 + r;
                if (erow < E) ebuf[(size_t)erow * 128 + col] = f2bf(acc[nt][r]);
            }
        }
    }
}

// ---------------------------------------------------------------------------
// CSR build
// ---------------------------------------------------------------------------
__global__ __launch_bounds__(256) void k_hist(
    const int* __restrict__ ei, int* __restrict__ counts, int E)
{
    int i = blockIdx.x * 256 + threadIdx.x;
    if (i < E) atomicAdd(&counts[ei[E + i]], 1);
}

__global__ __launch_bounds__(256) void k_scan_partial(
    const int* __restrict__ counts, int* __restrict__ partial, int N)
{
    const int base = blockIdx.x * SCAN_CHUNK;
    int v = 0;
    for (int i = threadIdx.x; i < SCAN_CHUNK; i += 256) {
        const int idx = base + i;
        if (idx < N) v += counts[idx];
    }
    __shared__ int red[4];
    #pragma unroll
    for (int off = 1; off < 64; off <<= 1) v += __shfl_xor(v, off);
    if ((threadIdx.x & 63) == 0) red[threadIdx.x >> 6] = v;
    __syncthreads();
    if (threadIdx.x == 0) partial[blockIdx.x] = red[0] + red[1] + red[2] + red[3];
}

__global__ __launch_bounds__(256) void k_scan_base(
    const int* __restrict__ partial, int* __restrict__ base, int nb)
{
    __shared__ int tmp[256];
    const int v = (threadIdx.x < nb) ? partial[threadIdx.x] : 0;
    tmp[threadIdx.x] = v;
    __syncthreads();
    for (int off = 1; off < 256; off <<= 1) {
        const int add = (threadIdx.x >= off) ? tmp[threadIdx.x - off] : 0;
        __syncthreads();
        tmp[threadIdx.x] += add;
        __syncthreads();
    }
    if (threadIdx.x < nb) base[threadIdx.x] = tmp[threadIdx.x] - v;
}

__global__ __launch_bounds__(256) void k_scan_final(
    const int* __restrict__ counts, const int* __restrict__ base,
    int* __restrict__ rowptr, int* __restrict__ cursor, int N)
{
    const int i0 = blockIdx.x * SCAN_CHUNK;
    __shared__ int tmp[256];
    const int ia = i0 + threadIdx.x * 2, ib = ia + 1;
    const int v0 = (ia < N) ? counts[ia] : 0;
    const int v1 = (ib < N) ? counts[ib] : 0;
    const int s = v0 + v1;
    tmp[threadIdx.x] = s;
    __syncthreads();
    for (int off = 1; off < 256; off <<= 1) {
        const int add = (threadIdx.x >= off) ? tmp[threadIdx.x - off] : 0;
        __syncthreads();
        tmp[threadIdx.x] += add;
        __syncthreads();
    }
    const int excl = tmp[threadIdx.x] - s + base[blockIdx.x];
    if (ia < N) { rowptr[ia] = excl;      cursor[ia] = excl; }
    if (ib < N) { rowptr[ib] = excl + v0; cursor[ib] = excl + v0; }
}

// fill: permutation + src gather + rel_t, all emitted in CSR-slot order
__global__ __launch_bounds__(256) void k_fill(
    const int* __restrict__ ei, const float* __restrict__ t,
    const float* __restrict__ lu, int* __restrict__ cursor,
    int* __restrict__ perm, int* __restrict__ srcp,
    float* __restrict__ relp, int E)
{
    int i = blockIdx.x * 256 + threadIdx.x;
    if (i < E) {
        const int s = ei[i];
        const int d = ei[E + i];
        const int pos = atomicAdd(&cursor[d], 1);
        perm[pos] = i;
        srcp[pos] = s;
        relp[pos] = t[i] - lu[s];
    }
}

// ---------------------------------------------------------------------------
// K3: fused aggregation. One wave per dst. Lane = (e2, h, 4 channels):
// e2 = l>>5 picks one of TWO edges per iteration, u32 = l&31 indexes the
// bf16x4 unit within the 128-wide row (head = u32>>4). 4-deep shfl reduce,
// cross-half combine once at the end. Sequential e/src reads (CSR order).
// ---------------------------------------------------------------------------
__global__ __launch_bounds__(256) void k_agg(
    const int* __restrict__ srcp,
    const int* __restrict__ rowptr, const int* __restrict__ counts,
    const uint2* __restrict__ qb2, const uint2* __restrict__ kb2,
    const uint2* __restrict__ vb2, const uint2* __restrict__ eb2,
    float4* __restrict__ out4, int N)
{
    const int d = blockIdx.x * 4 + (threadIdx.x >> 6);
    if (d >= N) return;
    const int l = threadIdx.x & 63;
    const int u32 = l & 31;
    const int e2 = l >> 5;
    const int start = rowptr[d];
    const int deg = counts[d];

    const float4 qv = unpack4(qb2[(size_t)d * 32 + u32]);
    float4 acc = make_float4(0.f, 0.f, 0.f, 0.f);
    float denom = 0.f;

    for (int i = 0; i < deg; i += 2) {
        const int off = i + e2;
        const bool valid = off < deg;
        const int ss = start + (valid ? off : 0);
        const int src = srcp[ss];
        const float4 kv = unpack4(kb2[(size_t)src * 32 + u32]);
        const float4 ev = unpack4(eb2[(size_t)ss * 32 + u32]);
        const float4 vv = unpack4(vb2[(size_t)src * 32 + u32]);
        float s = qv.x * (kv.x + ev.x) + qv.y * (kv.y + ev.y) +
                  qv.z * (kv.z + ev.z) + qv.w * (kv.w + ev.w);
        s += __shfl_xor(s, 1);
        s += __shfl_xor(s, 2);
        s += __shfl_xor(s, 4);
        s += __shfl_xor(s, 8);
        const float p = valid ? __expf(s * SCALE_ATTN) : 0.f;
        denom += p;
        acc.x = fmaf(p, vv.x + ev.x, acc.x);
        acc.y = fmaf(p, vv.y + ev.y, acc.y);
        acc.z = fmaf(p, vv.z + ev.z, acc.z);
        acc.w = fmaf(p, vv.w + ev.w, acc.w);
    }
    acc.x += __shfl_xor(acc.x, 32);
    acc.y += __shfl_xor(acc.y, 32);
    acc.z += __shfl_xor(acc.z, 32);
    acc.w += __shfl_xor(acc.w, 32);
    denom += __shfl_xor(denom, 32);

    if (l < 32) {
        const float inv = 1.f / (denom + 1e-16f);
        float4* o = out4 + (size_t)d * 32 + u32;
        const float4 cur = *o;                    // skip (from k_node v|skip pass)
        *o = make_float4(fmaf(acc.x, inv, cur.x), fmaf(acc.y, inv, cur.y),
                         fmaf(acc.z, inv, cur.z), fmaf(acc.w, inv, cur.w));
    }
}

// ---------------------------------------------------------------------------
extern "C" void kernel_launch(void* const* d_in, const int* in_sizes, int n_in,
                              void* d_out, int out_size, void* d_ws, size_t ws_size,
                              hipStream_t stream)
{
    const float* x   = (const float*)d_in[0];
    const float* lu  = (const float*)d_in[1];
    const int*   ei  = (const int*)d_in[2];
    const float* t   = (const float*)d_in[3];
    const float* msg = (const float*)d_in[4];
    const float* tw  = (const float*)d_in[5];
    const float* tb  = (const float*)d_in[6];
    const float* Wq  = (const float*)d_in[7];
    const float* bq  = (const float*)d_in[8];
    const float* Wk  = (const float*)d_in[9];
    const float* bk  = (const float*)d_in[10];
    const float* Wv  = (const float*)d_in[11];
    const float* bv  = (const float*)d_in[12];
    const float* We  = (const float*)d_in[13];
    const float* Wsk = (const float*)d_in[14];
    const float* bsk = (const float*)d_in[15];

    const int N = in_sizes[1];   // last_update: N elements
    const int E = in_sizes[3];   // t: E elements
    float* out = (float*)d_out;

    char* ws = (char*)d_ws;
    unsigned short* qb = (unsigned short*)ws;  ws += (size_t)N * 128 * sizeof(unsigned short);
    unsigned short* kb = (unsigned short*)ws;  ws += (size_t)N * 128 * sizeof(unsigned short);
    unsigned short* vb = (unsigned short*)ws;  ws += (size_t)N * 128 * sizeof(unsigned short);
    unsigned short* eb = (unsigned short*)ws;  ws += (size_t)E * 128 * sizeof(unsigned short);
    int*   counts  = (int*)ws;   ws += (size_t)N * sizeof(int);
    int*   rowptr  = (int*)ws;   ws += (size_t)N * sizeof(int);
    int*   cursor  = (int*)ws;   ws += (size_t)N * sizeof(int);
    int*   perm    = (int*)ws;   ws += (size_t)E * sizeof(int);
    int*   srcp    = (int*)ws;   ws += (size_t)E * sizeof(int);
    float* relp    = (float*)ws; ws += (size_t)E * sizeof(float);
    int*   partial = (int*)ws;   ws += 512 * sizeof(int);
    int*   baseArr = (int*)ws;   ws += 512 * sizeof(int);

    const int nScan = (N + SCAN_CHUNK - 1) / SCAN_CHUNK;

    hipMemsetAsync(counts, 0, (size_t)N * sizeof(int), stream);

    // CSR build first (independent of node/edge GEMMs)
    k_hist<<<(E + 255) / 256, 256, 0, stream>>>(ei, counts, E);
    k_scan_partial<<<nScan, 256, 0, stream>>>(counts, partial, N);
    k_scan_base<<<1, 256, 0, stream>>>(partial, baseArr, nScan);
    k_scan_final<<<nScan, 256, 0, stream>>>(counts, baseArr, rowptr, cursor, N);
    k_fill<<<(E + 255) / 256, 256, 0, stream>>>(ei, t, lu, cursor, perm, srcp, relp, E);

    // node linears: [q|k] then [v|skip->d_out]
    const int nTN = (N + 127) / 128;
    k_node_mfma<<<min(nTN, 512), 512, 0, stream>>>(
        (const float4*)x, Wq, Wk, bq, bk, qb, kb, nullptr, N, nTN);
    k_node_mfma<<<min(nTN, 512), 512, 0, stream>>>(
        (const float4*)x, Wv, Wsk, bv, bsk, vb, nullptr, out, N, nTN);

    // edge GEMM in CSR-slot order
    const int nTE = (E + 127) / 128;
    k_edge_mfma<<<min(nTE, 1024), 512, 0, stream>>>(
        (const float4*)msg, perm, relp,
        (const float4*)tw, (const float4*)tb, We, eb, E, nTE);

    // fused aggregation (sequential e/src streams, no atomics)
    k_agg<<<(N + 3) / 4, 256, 0, stream>>>(
        srcp, rowptr, counts,
        (const uint2*)qb, (const uint2*)kb, (const uint2*)vb, (const uint2*)eb,
        (float4*)out, N);
}